// Round 12
// baseline (742.067 us; speedup 1.0000x reference)
//
#include <hip/hip_runtime.h>
#include <math.h>

#define N 8192
#define C 128
#define NC 256
#define KNN 5

#define TP 128                        // tile size
#define NTILE (N / TP)                // 64
#define NPAIR (NTILE * (NTILE + 1) / 2)   // 2080
#define CH 16                         // channels per staging chunk
#define PJ 130                        // LDS pitch over row-dim (doubles)
#define SQRT_C 11.313708498984761     // sqrt(128)

static __device__ __forceinline__ unsigned rotl32(unsigned x, unsigned r) {
    return (x << r) | (x >> (32u - r));
}

// order-preserving double -> uint64 map (ascending)
static __device__ __forceinline__ unsigned long long dmap(double x) {
    long long b = __double_as_longlong(x);
    unsigned long long u = (unsigned long long)b;
    return (b >= 0) ? (u | 0x8000000000000000ull) : ~u;
}
static __device__ __forceinline__ double dunmap(unsigned long long u) {
    if (u & 0x8000000000000000ull) return __longlong_as_double((long long)(u ^ 0x8000000000000000ull));
    return __longlong_as_double((long long)(~u));
}

// keep 5 smallest; m5[0] holds current max of the 5
static __device__ __forceinline__ void ins5(double (&m5)[KNN], double v) {
    if (v < m5[0]) {
        m5[0] = v;
        #pragma unroll
        for (int k = 1; k < KNN; k++)
            if (m5[k] > m5[0]) { double tmp = m5[0]; m5[0] = m5[k]; m5[k] = tmp; }
    }
}

// SAFE butterfly top-5 merge: snapshot partner's 5 values BEFORE any insertion.
static __device__ __forceinline__ void bfly5(double (&m5)[KNN], int mask) {
    double pv[KNN];
    #pragma unroll
    for (int k = 0; k < KNN; k++) pv[k] = __shfl_xor(m5[k], mask, 64);
    #pragma unroll
    for (int k = 0; k < KNN; k++) ins5(m5, pv[k]);
}

// ---------------------------------------------------------------------------
__global__ void init_kernel(unsigned long long* d2max, unsigned long long* gmin) {
    int i = blockIdx.x * blockDim.x + threadIdx.x;
    if (i < N) gmin[i] = 0xFFFFFFFFFFFFFFFFull;
    if (i == 0) *d2max = 0ull;
}

// ---------------------------------------------------------------------------
__global__ void sq_kernel(const float* __restrict__ X, double* __restrict__ sq) {
    int wave = (blockIdx.x * blockDim.x + threadIdx.x) >> 6;
    int lane = threadIdx.x & 63;
    if (wave >= N) return;
    double v0 = (double)X[wave * C + lane];
    double v1 = (double)X[wave * C + 64 + lane];
    double s = v0 * v0 + v1 * v1;
    #pragma unroll
    for (int off = 32; off > 0; off >>= 1) s += __shfl_down(s, off, 64);
    if (lane == 0) sq[wave] = s;
}

// ---------------------------------------------------------------------------
// JAX threefry2x32: uniform(key(1), (1,8192))
// ---------------------------------------------------------------------------
__global__ void noise_kernel(float* __restrict__ noise) {
    int j = blockIdx.x * blockDim.x + threadIdx.x;
    if (j >= N / 2) return;
    const unsigned ks0 = 0u, ks1 = 1u;
    const unsigned ks2 = 0x1BD11BDAu ^ ks0 ^ ks1;
    unsigned x0 = (unsigned)j + ks0;
    unsigned x1 = (unsigned)(j + N / 2) + ks1;
    const unsigned rotA[4] = {13u, 15u, 26u, 6u};
    const unsigned rotB[4] = {17u, 29u, 16u, 24u};
    #pragma unroll
    for (int r = 0; r < 4; r++) { x0 += x1; x1 = rotl32(x1, rotA[r]); x1 ^= x0; }
    x0 += ks1; x1 += ks2 + 1u;
    #pragma unroll
    for (int r = 0; r < 4; r++) { x0 += x1; x1 = rotl32(x1, rotB[r]); x1 ^= x0; }
    x0 += ks2; x1 += ks0 + 2u;
    #pragma unroll
    for (int r = 0; r < 4; r++) { x0 += x1; x1 = rotl32(x1, rotA[r]); x1 ^= x0; }
    x0 += ks0; x1 += ks1 + 3u;
    #pragma unroll
    for (int r = 0; r < 4; r++) { x0 += x1; x1 = rotl32(x1, rotB[r]); x1 ^= x0; }
    x0 += ks1; x1 += ks2 + 4u;
    #pragma unroll
    for (int r = 0; r < 4; r++) { x0 += x1; x1 = rotl32(x1, rotA[r]); x1 ^= x0; }
    x0 += ks2; x1 += ks0 + 5u;
    unsigned b0 = (x0 >> 9) | 0x3f800000u;
    unsigned b1 = (x1 >> 9) | 0x3f800000u;
    noise[j]         = __uint_as_float(b0) - 1.0f;
    noise[j + N / 2] = __uint_as_float(b1) - 1.0f;
}

// p = bj*(bj+1)/2 + bi, bi <= bj
static __device__ __forceinline__ void pair_decode(int p, int& bi, int& bj) {
    int b = (int)((sqrt(8.0 * (double)p + 1.0) - 1.0) * 0.5);
    while ((b + 1) * (b + 2) / 2 <= p) b++;
    while (b * (b + 1) / 2 > p) b--;
    bj = b;
    bi = p - b * (b + 1) / 2;
}

// ---------------------------------------------------------------------------
// GEMM body: 128x128 tile-pair, 8x8/thread, f64 [c][row] staging (pitch PJ),
// 8 chunks of 16 channels, register prefetch.  All LDS reads are b128:
//   rows/thread: 8*ty + r (contiguous 8 -> 4x double2, broadcast over tx)
//   cols/thread: 32*h + 2*tx + b (pairs -> 4x double2, conflict-free)
// ---------------------------------------------------------------------------
#define GEMM_BODY(acc, As, Bs, X4, i0, j0, t, tx, ty)                          \
    {                                                                          \
        float4 pa[2], pb[2];                                                   \
        _Pragma("unroll")                                                      \
        for (int q = 0; q < 2; q++) {                                          \
            int flat = t + 256 * q;                                            \
            int row = flat >> 2, c4 = flat & 3;                                \
            pa[q] = X4[(size_t)(i0 + row) * 32 + c4];                          \
            pb[q] = X4[(size_t)(j0 + row) * 32 + c4];                          \
        }                                                                      \
        for (int ck = 0; ck < 8; ck++) {                                       \
            _Pragma("unroll")                                                  \
            for (int q = 0; q < 2; q++) {                                      \
                int flat = t + 256 * q;                                        \
                int row = flat >> 2, c4 = flat & 3;                            \
                As[(4 * c4 + 0) * PJ + row] = (double)pa[q].x;                 \
                As[(4 * c4 + 1) * PJ + row] = (double)pa[q].y;                 \
                As[(4 * c4 + 2) * PJ + row] = (double)pa[q].z;                 \
                As[(4 * c4 + 3) * PJ + row] = (double)pa[q].w;                 \
                Bs[(4 * c4 + 0) * PJ + row] = (double)pb[q].x;                 \
                Bs[(4 * c4 + 1) * PJ + row] = (double)pb[q].y;                 \
                Bs[(4 * c4 + 2) * PJ + row] = (double)pb[q].z;                 \
                Bs[(4 * c4 + 3) * PJ + row] = (double)pb[q].w;                 \
            }                                                                  \
            __syncthreads();                                                   \
            if (ck < 7) {                                                      \
                _Pragma("unroll")                                              \
                for (int q = 0; q < 2; q++) {                                  \
                    int flat = t + 256 * q;                                    \
                    int row = flat >> 2, c4 = flat & 3;                        \
                    pa[q] = X4[(size_t)(i0 + row) * 32 + (ck + 1) * 4 + c4];   \
                    pb[q] = X4[(size_t)(j0 + row) * 32 + (ck + 1) * 4 + c4];   \
                }                                                              \
            }                                                                  \
            _Pragma("unroll 2")                                                \
            for (int c = 0; c < CH; c++) {                                     \
                double a[8], b[8];                                             \
                _Pragma("unroll")                                              \
                for (int p2 = 0; p2 < 4; p2++) {                               \
                    double2 av = *(const double2*)&As[c * PJ + 8 * ty + 2 * p2]; \
                    a[2 * p2] = av.x; a[2 * p2 + 1] = av.y;                    \
                }                                                              \
                _Pragma("unroll")                                              \
                for (int h = 0; h < 4; h++) {                                  \
                    double2 bv = *(const double2*)&Bs[c * PJ + 32 * h + 2 * tx]; \
                    b[2 * h] = bv.x; b[2 * h + 1] = bv.y;                      \
                }                                                              \
                _Pragma("unroll")                                              \
                for (int r = 0; r < 8; r++)                                    \
                    _Pragma("unroll")                                          \
                    for (int s = 0; s < 8; s++)                                \
                        acc[r][s] += a[r] * b[s];                              \
            }                                                                  \
            __syncthreads();                                                   \
        }                                                                      \
    }

// row owned: 8*ty + r ; col owned: 32*(s>>1) + 2*tx + (s&1)

// ---------------------------------------------------------------------------
// symA: tile-pair d2 GEMM + streaming shuffle top-5 epilogue (low reg) + d2max.
// ---------------------------------------------------------------------------
__launch_bounds__(256, 2)
__global__ void symA_kernel(const float* __restrict__ X,
                            const double* __restrict__ sq,
                            double* __restrict__ rec_dir,
                            double* __restrict__ rec_tr,
                            unsigned long long* __restrict__ d2max_p)
{
    __shared__ __align__(16) double S[2 * CH * PJ];   // 33,280 B; reused as M
    __shared__ double wred[4];
    double* As = S;
    double* Bs = S + CH * PJ;

    const int t  = threadIdx.x;
    const int tx = t & 15;
    const int ty = t >> 4;
    int bi, bj;
    pair_decode(blockIdx.x, bi, bj);
    const int i0 = bi * TP, j0 = bj * TP;
    const float4* X4 = (const float4*)X;

    double acc[8][8];
    #pragma unroll
    for (int r = 0; r < 8; r++)
        #pragma unroll
        for (int s = 0; s < 8; s++) acc[r][s] = 0.0;

    GEMM_BODY(acc, As, Bs, X4, i0, j0, t, tx, ty)

    // d2 in place + block max
    double sqa[8], sqj[8];
    #pragma unroll
    for (int r = 0; r < 8; r++) sqa[r] = sq[i0 + 8 * ty + r];
    #pragma unroll
    for (int s = 0; s < 8; s++) sqj[s] = sq[j0 + 32 * (s >> 1) + 2 * tx + (s & 1)];
    double rmax = 0.0;
    #pragma unroll
    for (int r = 0; r < 8; r++)
        #pragma unroll
        for (int s = 0; s < 8; s++) {
            double v = sqa[r] + sqj[s] - 2.0 * acc[r][s];
            acc[r][s] = v;
            rmax = fmax(rmax, v);
        }
    #pragma unroll
    for (int off = 32; off > 0; off >>= 1) rmax = fmax(rmax, __shfl_down(rmax, off, 64));
    if ((t & 63) == 0) wred[t >> 6] = rmax;

    // ---- rows: one m5 at a time; butterfly over 16 tx lanes; root writes
    #pragma unroll
    for (int r = 0; r < 8; r++) {
        double m5[KNN];
        #pragma unroll
        for (int k = 0; k < KNN; k++) m5[k] = 1e300;
        #pragma unroll
        for (int s = 0; s < 8; s++) ins5(m5, acc[r][s]);
        bfly5(m5, 1); bfly5(m5, 2); bfly5(m5, 4); bfly5(m5, 8);
        if (tx == 0) {
            double* outp = &rec_dir[(size_t)blockIdx.x * (TP * KNN) + (8 * ty + r) * KNN];
            #pragma unroll
            for (int k = 0; k < KNN; k++) outp[k] = m5[k];
        }
    }

    // ---- cols (off-diagonal): one col at a time (low register pressure),
    //      intra-wave ty butterfly, wave-roots -> LDS partials, final merge.
    if (bi != bj) {
        double* M = S;   // [col][21] : 4 wave-partials x 5
        const int w = t >> 6;
        // GEMM_BODY ended with __syncthreads(); rows touch no LDS -> M safe
        #pragma unroll
        for (int s = 0; s < 8; s++) {
            double m5[KNN];
            #pragma unroll
            for (int k = 0; k < KNN; k++) m5[k] = 1e300;
            #pragma unroll
            for (int r = 0; r < 8; r++) ins5(m5, acc[r][s]);
            bfly5(m5, 16); bfly5(m5, 32);
            if (((t >> 4) & 3) == 0) {
                int col = 32 * (s >> 1) + 2 * tx + (s & 1);
                #pragma unroll
                for (int k = 0; k < KNN; k++) M[col * 21 + w * 5 + k] = m5[k];
            }
        }
        __syncthreads();
        if (t == 0)
            atomicMax(d2max_p, (unsigned long long)__double_as_longlong(
                fmax(fmax(fmax(wred[0], wred[1]), fmax(wred[2], wred[3])), 0.0)));
        if (t < 128) {
            double m5[KNN];
            #pragma unroll
            for (int k = 0; k < KNN; k++) m5[k] = 1e300;
            const double* row = &M[t * 21];
            #pragma unroll
            for (int q = 0; q < 20; q++) ins5(m5, row[q]);
            double* outp = &rec_tr[(size_t)blockIdx.x * (TP * KNN) + t * KNN];
            #pragma unroll
            for (int k = 0; k < KNN; k++) outp[k] = m5[k];
        }
    } else {
        __syncthreads();
        if (t == 0)
            atomicMax(d2max_p, (unsigned long long)__double_as_longlong(
                fmax(fmax(fmax(wred[0], wred[1]), fmax(wred[2], wred[3])), 0.0)));
    }
}

// ---------------------------------------------------------------------------
// Merge symA records -> density.
// ---------------------------------------------------------------------------
__global__ void density_merge_sym_kernel(const double* __restrict__ rec_dir,
                                         const double* __restrict__ rec_tr,
                                         const float* __restrict__ noise,
                                         double* __restrict__ density)
{
    int i = blockIdx.x * blockDim.x + threadIdx.x;
    if (i >= N) return;
    int T = i >> 7, r = i & 127;
    double t5[KNN];
    #pragma unroll
    for (int k = 0; k < KNN; k++) t5[k] = 1e300;

    for (int bj = T; bj < NTILE; bj++) {
        int p = bj * (bj + 1) / 2 + T;
        const double* rp = &rec_dir[(size_t)p * (TP * KNN) + r * KNN];
        #pragma unroll
        for (int k = 0; k < KNN; k++) ins5(t5, rp[k]);
    }
    int cumT = T * (T + 1) / 2;
    for (int b2 = 0; b2 < T; b2++) {
        const double* rp = &rec_tr[(size_t)(cumT + b2) * (TP * KNN) + r * KNN];
        #pragma unroll
        for (int k = 0; k < KNN; k++) ins5(t5, rp[k]);
    }
    for (int a = 1; a < KNN; a++) {
        double key = t5[a]; int b = a - 1;
        while (b >= 0 && t5[b] > key) { t5[b + 1] = t5[b]; b--; }
        t5[b + 1] = key;
    }
    double s2 = 0.0;
    #pragma unroll
    for (int k = 0; k < KNN; k++) {
        double z = t5[k] > 0.0 ? t5[k] : 0.0;
        double d = sqrt(z) / SQRT_C;
        s2 += d * d;
    }
    density[i] = exp(-s2 / 5.0) + (double)(noise[i] * 1e-6f);
}

// ---------------------------------------------------------------------------
// symB: tile-pair GEMM + masked row/col mins, shuffle-reduced, atomicMin.
// ---------------------------------------------------------------------------
__launch_bounds__(256, 2)
__global__ void symB_kernel(const float* __restrict__ X,
                            const double* __restrict__ sq,
                            const double* __restrict__ density,
                            unsigned long long* __restrict__ gmin)
{
    __shared__ __align__(16) double S[2 * CH * PJ];
    __shared__ double Drow[TP], Dcol[TP];
    double* As = S;
    double* Bs = S + CH * PJ;

    const int t  = threadIdx.x;
    const int tx = t & 15;
    const int ty = t >> 4;
    int bi, bj;
    pair_decode(blockIdx.x, bi, bj);
    const int i0 = bi * TP, j0 = bj * TP;
    const float4* X4 = (const float4*)X;

    if (t < 128) Drow[t] = density[i0 + t];
    else Dcol[t - 128] = density[j0 + t - 128];
    __syncthreads();

    double acc[8][8];
    #pragma unroll
    for (int r = 0; r < 8; r++)
        #pragma unroll
        for (int s = 0; s < 8; s++) acc[r][s] = 0.0;

    GEMM_BODY(acc, As, Bs, X4, i0, j0, t, tx, ty)

    double sqa[8], sqj[8], di[8], dj[8], dmr[8], dmc[8];
    #pragma unroll
    for (int r = 0; r < 8; r++) { sqa[r] = sq[i0 + 8 * ty + r]; di[r] = Drow[8 * ty + r]; dmr[r] = 1e300; }
    #pragma unroll
    for (int s = 0; s < 8; s++) {
        int col = 32 * (s >> 1) + 2 * tx + (s & 1);
        sqj[s] = sq[j0 + col];
        dj[s] = Dcol[col];
        dmc[s] = 1e300;
    }

    #pragma unroll
    for (int r = 0; r < 8; r++)
        #pragma unroll
        for (int s = 0; s < 8; s++) {
            double v = sqa[r] + sqj[s] - 2.0 * acc[r][s];
            if (dj[s] > di[r]) dmr[r] = fmin(dmr[r], v);
            if (di[r] > dj[s]) dmc[s] = fmin(dmc[s], v);
        }

    // rows: butterfly min over tx lanes; root atomicMin (scalar bfly is safe)
    #pragma unroll
    for (int r = 0; r < 8; r++) {
        #pragma unroll
        for (int m = 1; m <= 8; m <<= 1)
            dmr[r] = fmin(dmr[r], __shfl_xor(dmr[r], m, 64));
    }
    if (tx == 0) {
        #pragma unroll
        for (int r = 0; r < 8; r++)
            if (dmr[r] < 9.9e299) atomicMin(&gmin[i0 + 8 * ty + r], dmap(dmr[r]));
    }
    // cols: intra-wave ty butterfly; wave-root atomicMin (4 per col)
    if (bi != bj) {
        #pragma unroll
        for (int s = 0; s < 8; s++) {
            #pragma unroll
            for (int m = 16; m <= 32; m <<= 1)
                dmc[s] = fmin(dmc[s], __shfl_xor(dmc[s], m, 64));
        }
        if (((t >> 4) & 3) == 0) {
            #pragma unroll
            for (int s = 0; s < 8; s++) {
                if (dmc[s] < 9.9e299) {
                    int col = 32 * (s >> 1) + 2 * tx + (s & 1);
                    atomicMin(&gmin[j0 + col], dmap(dmc[s]));
                }
            }
        }
    }
}

// ---------------------------------------------------------------------------
__global__ void score_sym_kernel(const unsigned long long* __restrict__ gmin,
                                 const double* __restrict__ density,
                                 const unsigned long long* __restrict__ d2max_p,
                                 double* __restrict__ score)
{
    int i = blockIdx.x * blockDim.x + threadIdx.x;
    if (i >= N) return;
    unsigned long long u = gmin[i];
    double d2m = __longlong_as_double((long long)(*d2max_p));
    double distmax = sqrt(fmax(d2m, 0.0)) / SQRT_C;
    double dp;
    if (u == 0xFFFFFFFFFFFFFFFFull) {
        dp = distmax;
    } else {
        double dmin = dunmap(u);
        dp = sqrt(fmax(dmin, 0.0)) / SQRT_C;
    }
    score[i] = dp * density[i];
}

// ---------------------------------------------------------------------------
// Stable descending rank; 256 blocks, 8-way j-split per row, shuffle reduce.
// ---------------------------------------------------------------------------
__launch_bounds__(256)
__global__ void rank_kernel(const double* __restrict__ score, int* __restrict__ out)
{
    __shared__ double Ss[N];   // 64 KB
    for (int k = 0; k < N / 256; k++) {
        int idx = threadIdx.x + 256 * k;
        Ss[idx] = score[idx];
    }
    __syncthreads();
    int il = threadIdx.x >> 3;          // 0..31
    int ch = threadIdx.x & 7;           // 0..7
    int i = blockIdx.x * 32 + il;
    double si = Ss[i];
    int cnt = 0;
    for (int q = 0; q < N / 8; q++) {
        int j = ch + (q << 3);
        double sj = Ss[j];
        cnt += (sj > si) || (sj == si && j < i);
    }
    cnt += __shfl_down(cnt, 4, 8);
    cnt += __shfl_down(cnt, 2, 8);
    cnt += __shfl_down(cnt, 1, 8);
    if (ch == 0 && cnt < NC) out[cnt] = i;
}

// ---------------------------------------------------------------------------
extern "C" void kernel_launch(void* const* d_in, const int* in_sizes, int n_in,
                              void* d_out, int out_size, void* d_ws, size_t ws_size,
                              hipStream_t stream) {
    const float* X = (const float*)d_in[0];
    int* out = (int*)d_out;

    double* ws      = (double*)d_ws;
    double* sq      = ws;                      // 8192
    double* density = ws + 8192;               // 8192
    double* score   = ws + 16384;              // 8192
    unsigned long long* d2max = (unsigned long long*)(ws + 24576);
    unsigned long long* gmin  = (unsigned long long*)(ws + 24584);  // 8192
    float*  noise   = (float*)(ws + 32776);    // 8192 floats

    const size_t rec_bytes = (size_t)NPAIR * TP * KNN * sizeof(double);  // 10.65 MB
    const size_t base_need = 4ull * 1024 * 1024;
    double* rec_dir = (double*)((char*)d_ws + base_need);
    double* rec_tr  = (double*)((char*)d_ws + base_need + rec_bytes);

    init_kernel<<<N / 256, 256, 0, stream>>>(d2max, gmin);
    sq_kernel<<<N / 4, 256, 0, stream>>>(X, sq);
    noise_kernel<<<(N / 2) / 256, 256, 0, stream>>>(noise);

    symA_kernel<<<NPAIR, 256, 0, stream>>>(X, sq, rec_dir, rec_tr, d2max);
    density_merge_sym_kernel<<<N / 256, 256, 0, stream>>>(rec_dir, rec_tr, noise, density);
    symB_kernel<<<NPAIR, 256, 0, stream>>>(X, sq, density, gmin);
    score_sym_kernel<<<N / 256, 256, 0, stream>>>(gmin, density, d2max, score);
    rank_kernel<<<N / 32, 256, 0, stream>>>(score, out);
}

// Round 13
// 533.336 us; speedup vs baseline: 1.3914x; 1.3914x over previous
//
#include <hip/hip_runtime.h>
#include <math.h>

#define N 8192
#define C 128
#define NC 256
#define KNN 5

#define TP 128                        // tile size
#define NTILE (N / TP)                // 64
#define NPAIR (NTILE * (NTILE + 1) / 2)   // 2080
#define CH 16                         // channels per staging chunk
#define PJ 130                        // LDS pitch over row-dim (doubles)
#define SQRT_C 11.313708498984761     // sqrt(128)

static __device__ __forceinline__ unsigned rotl32(unsigned x, unsigned r) {
    return (x << r) | (x >> (32u - r));
}

// order-preserving double -> uint64 map (ascending)
static __device__ __forceinline__ unsigned long long dmap(double x) {
    long long b = __double_as_longlong(x);
    unsigned long long u = (unsigned long long)b;
    return (b >= 0) ? (u | 0x8000000000000000ull) : ~u;
}
static __device__ __forceinline__ double dunmap(unsigned long long u) {
    if (u & 0x8000000000000000ull) return __longlong_as_double((long long)(u ^ 0x8000000000000000ull));
    return __longlong_as_double((long long)(~u));
}

// ---------------------------------------------------------------------------
// Branchless sorted top-5 (ascending: m[0] <= ... <= m[4], 5 smallest seen).
// Insert: 9 f64 min/max, no divergence.
static __device__ __forceinline__ void ins5s(double (&m)[KNN], double v) {
    m[4] = fmin(m[4], fmax(m[3], v));
    m[3] = fmin(m[3], fmax(m[2], v));
    m[2] = fmin(m[2], fmax(m[1], v));
    m[1] = fmin(m[1], fmax(m[0], v));
    m[0] = fmin(m[0], v);
}

// 9-CE sorting network for 5 elements (classic Knuth network).
static __device__ __forceinline__ void sort5(double (&m)[KNN]) {
    double lo, hi;
#define CE(i, j) lo = fmin(m[i], m[j]); hi = fmax(m[i], m[j]); m[i] = lo; m[j] = hi;
    CE(0,1) CE(3,4) CE(2,4) CE(2,3) CE(0,3) CE(0,2) CE(1,4) CE(1,3) CE(1,2)
#undef CE
}

// Merge sorted partner (via reversed-index shuffle) using the bitonic top-k
// identity: 5 smallest of (a ∪ b) = { min(a_i, b_{4-i}) }, then re-sort.
// Snapshot-before-mutate: all shuffles read pristine state.
static __device__ __forceinline__ void bfly5s(double (&m)[KNN], int mask) {
    double pv[KNN];
    #pragma unroll
    for (int k = 0; k < KNN; k++) pv[k] = __shfl_xor(m[4 - k], mask, 64);
    #pragma unroll
    for (int k = 0; k < KNN; k++) m[k] = fmin(m[k], pv[k]);
    sort5(m);
}

// Merge a sorted-5 list read from memory (l) into sorted m.
static __device__ __forceinline__ void merge5s(double (&m)[KNN], const double* l) {
    #pragma unroll
    for (int k = 0; k < KNN; k++) m[k] = fmin(m[k], l[4 - k]);
    sort5(m);
}

// ---------------------------------------------------------------------------
__global__ void init_kernel(unsigned long long* d2max, unsigned long long* gmin) {
    int i = blockIdx.x * blockDim.x + threadIdx.x;
    if (i < N) gmin[i] = 0xFFFFFFFFFFFFFFFFull;
    if (i == 0) *d2max = 0ull;
}

// ---------------------------------------------------------------------------
__global__ void sq_kernel(const float* __restrict__ X, double* __restrict__ sq) {
    int wave = (blockIdx.x * blockDim.x + threadIdx.x) >> 6;
    int lane = threadIdx.x & 63;
    if (wave >= N) return;
    double v0 = (double)X[wave * C + lane];
    double v1 = (double)X[wave * C + 64 + lane];
    double s = v0 * v0 + v1 * v1;
    #pragma unroll
    for (int off = 32; off > 0; off >>= 1) s += __shfl_down(s, off, 64);
    if (lane == 0) sq[wave] = s;
}

// ---------------------------------------------------------------------------
// JAX threefry2x32: uniform(key(1), (1,8192))
// ---------------------------------------------------------------------------
__global__ void noise_kernel(float* __restrict__ noise) {
    int j = blockIdx.x * blockDim.x + threadIdx.x;
    if (j >= N / 2) return;
    const unsigned ks0 = 0u, ks1 = 1u;
    const unsigned ks2 = 0x1BD11BDAu ^ ks0 ^ ks1;
    unsigned x0 = (unsigned)j + ks0;
    unsigned x1 = (unsigned)(j + N / 2) + ks1;
    const unsigned rotA[4] = {13u, 15u, 26u, 6u};
    const unsigned rotB[4] = {17u, 29u, 16u, 24u};
    #pragma unroll
    for (int r = 0; r < 4; r++) { x0 += x1; x1 = rotl32(x1, rotA[r]); x1 ^= x0; }
    x0 += ks1; x1 += ks2 + 1u;
    #pragma unroll
    for (int r = 0; r < 4; r++) { x0 += x1; x1 = rotl32(x1, rotB[r]); x1 ^= x0; }
    x0 += ks2; x1 += ks0 + 2u;
    #pragma unroll
    for (int r = 0; r < 4; r++) { x0 += x1; x1 = rotl32(x1, rotA[r]); x1 ^= x0; }
    x0 += ks0; x1 += ks1 + 3u;
    #pragma unroll
    for (int r = 0; r < 4; r++) { x0 += x1; x1 = rotl32(x1, rotB[r]); x1 ^= x0; }
    x0 += ks1; x1 += ks2 + 4u;
    #pragma unroll
    for (int r = 0; r < 4; r++) { x0 += x1; x1 = rotl32(x1, rotA[r]); x1 ^= x0; }
    x0 += ks2; x1 += ks0 + 5u;
    unsigned b0 = (x0 >> 9) | 0x3f800000u;
    unsigned b1 = (x1 >> 9) | 0x3f800000u;
    noise[j]         = __uint_as_float(b0) - 1.0f;
    noise[j + N / 2] = __uint_as_float(b1) - 1.0f;
}

// p = bj*(bj+1)/2 + bi, bi <= bj
static __device__ __forceinline__ void pair_decode(int p, int& bi, int& bj) {
    int b = (int)((sqrt(8.0 * (double)p + 1.0) - 1.0) * 0.5);
    while ((b + 1) * (b + 2) / 2 <= p) b++;
    while (b * (b + 1) / 2 > p) b--;
    bj = b;
    bi = p - b * (b + 1) / 2;
}

// ---------------------------------------------------------------------------
// GEMM body: 128x128 tile-pair, 8x8/thread, f64 [c][row] staging (pitch PJ),
// 8 chunks of 16 channels, register prefetch.  All LDS reads are b128.
// row owned: 8*ty + r ; col owned: 32*(s>>1) + 2*tx + (s&1)
// ---------------------------------------------------------------------------
#define GEMM_BODY(acc, As, Bs, X4, i0, j0, t, tx, ty)                          \
    {                                                                          \
        float4 pa[2], pb[2];                                                   \
        _Pragma("unroll")                                                      \
        for (int q = 0; q < 2; q++) {                                          \
            int flat = t + 256 * q;                                            \
            int row = flat >> 2, c4 = flat & 3;                                \
            pa[q] = X4[(size_t)(i0 + row) * 32 + c4];                          \
            pb[q] = X4[(size_t)(j0 + row) * 32 + c4];                          \
        }                                                                      \
        for (int ck = 0; ck < 8; ck++) {                                       \
            _Pragma("unroll")                                                  \
            for (int q = 0; q < 2; q++) {                                      \
                int flat = t + 256 * q;                                        \
                int row = flat >> 2, c4 = flat & 3;                            \
                As[(4 * c4 + 0) * PJ + row] = (double)pa[q].x;                 \
                As[(4 * c4 + 1) * PJ + row] = (double)pa[q].y;                 \
                As[(4 * c4 + 2) * PJ + row] = (double)pa[q].z;                 \
                As[(4 * c4 + 3) * PJ + row] = (double)pa[q].w;                 \
                Bs[(4 * c4 + 0) * PJ + row] = (double)pb[q].x;                 \
                Bs[(4 * c4 + 1) * PJ + row] = (double)pb[q].y;                 \
                Bs[(4 * c4 + 2) * PJ + row] = (double)pb[q].z;                 \
                Bs[(4 * c4 + 3) * PJ + row] = (double)pb[q].w;                 \
            }                                                                  \
            __syncthreads();                                                   \
            if (ck < 7) {                                                      \
                _Pragma("unroll")                                              \
                for (int q = 0; q < 2; q++) {                                  \
                    int flat = t + 256 * q;                                    \
                    int row = flat >> 2, c4 = flat & 3;                        \
                    pa[q] = X4[(size_t)(i0 + row) * 32 + (ck + 1) * 4 + c4];   \
                    pb[q] = X4[(size_t)(j0 + row) * 32 + (ck + 1) * 4 + c4];   \
                }                                                              \
            }                                                                  \
            _Pragma("unroll 2")                                                \
            for (int c = 0; c < CH; c++) {                                     \
                double a[8], b[8];                                             \
                _Pragma("unroll")                                              \
                for (int p2 = 0; p2 < 4; p2++) {                               \
                    double2 av = *(const double2*)&As[c * PJ + 8 * ty + 2 * p2]; \
                    a[2 * p2] = av.x; a[2 * p2 + 1] = av.y;                    \
                }                                                              \
                _Pragma("unroll")                                              \
                for (int h = 0; h < 4; h++) {                                  \
                    double2 bv = *(const double2*)&Bs[c * PJ + 32 * h + 2 * tx]; \
                    b[2 * h] = bv.x; b[2 * h + 1] = bv.y;                      \
                }                                                              \
                _Pragma("unroll")                                              \
                for (int r = 0; r < 8; r++)                                    \
                    _Pragma("unroll")                                          \
                    for (int s = 0; s < 8; s++)                                \
                        acc[r][s] += a[r] * b[s];                              \
            }                                                                  \
            __syncthreads();                                                   \
        }                                                                      \
    }

// ---------------------------------------------------------------------------
// symA: tile-pair d2 GEMM + branchless sorted top-5 epilogue + d2max.
// Records are stored SORTED ASCENDING.
// ---------------------------------------------------------------------------
__launch_bounds__(256, 2)
__global__ void symA_kernel(const float* __restrict__ X,
                            const double* __restrict__ sq,
                            double* __restrict__ rec_dir,
                            double* __restrict__ rec_tr,
                            unsigned long long* __restrict__ d2max_p)
{
    __shared__ __align__(16) double S[2 * CH * PJ];   // 33,280 B; reused as M
    __shared__ double wred[4];
    double* As = S;
    double* Bs = S + CH * PJ;

    const int t  = threadIdx.x;
    const int tx = t & 15;
    const int ty = t >> 4;
    int bi, bj;
    pair_decode(blockIdx.x, bi, bj);
    const int i0 = bi * TP, j0 = bj * TP;
    const float4* X4 = (const float4*)X;

    double acc[8][8];
    #pragma unroll
    for (int r = 0; r < 8; r++)
        #pragma unroll
        for (int s = 0; s < 8; s++) acc[r][s] = 0.0;

    GEMM_BODY(acc, As, Bs, X4, i0, j0, t, tx, ty)

    // d2 in place + block max
    double sqa[8], sqj[8];
    #pragma unroll
    for (int r = 0; r < 8; r++) sqa[r] = sq[i0 + 8 * ty + r];
    #pragma unroll
    for (int s = 0; s < 8; s++) sqj[s] = sq[j0 + 32 * (s >> 1) + 2 * tx + (s & 1)];
    double rmax = 0.0;
    #pragma unroll
    for (int r = 0; r < 8; r++)
        #pragma unroll
        for (int s = 0; s < 8; s++) {
            double v = sqa[r] + sqj[s] - 2.0 * acc[r][s];
            acc[r][s] = v;
            rmax = fmax(rmax, v);
        }
    #pragma unroll
    for (int off = 32; off > 0; off >>= 1) rmax = fmax(rmax, __shfl_down(rmax, off, 64));
    if ((t & 63) == 0) wred[t >> 6] = rmax;

    // ---- rows: branchless sorted scan + bitonic bfly merges over 16 tx lanes
    #pragma unroll
    for (int r = 0; r < 8; r++) {
        double m5[KNN];
        #pragma unroll
        for (int k = 0; k < KNN; k++) m5[k] = 1e300;
        #pragma unroll
        for (int s = 0; s < 8; s++) ins5s(m5, acc[r][s]);
        bfly5s(m5, 1); bfly5s(m5, 2); bfly5s(m5, 4); bfly5s(m5, 8);
        if (tx == 0) {
            double* outp = &rec_dir[(size_t)blockIdx.x * (TP * KNN) + (8 * ty + r) * KNN];
            #pragma unroll
            for (int k = 0; k < KNN; k++) outp[k] = m5[k];
        }
    }

    // ---- cols (off-diagonal): sorted scan + 2 bfly stages, wave-roots -> LDS
    if (bi != bj) {
        double* M = S;   // [col][21] : 4 wave-partials x 5
        const int w = t >> 6;
        #pragma unroll
        for (int s = 0; s < 8; s++) {
            double m5[KNN];
            #pragma unroll
            for (int k = 0; k < KNN; k++) m5[k] = 1e300;
            #pragma unroll
            for (int r = 0; r < 8; r++) ins5s(m5, acc[r][s]);
            bfly5s(m5, 16); bfly5s(m5, 32);
            if (((t >> 4) & 3) == 0) {
                int col = 32 * (s >> 1) + 2 * tx + (s & 1);
                #pragma unroll
                for (int k = 0; k < KNN; k++) M[col * 21 + w * 5 + k] = m5[k];
            }
        }
        __syncthreads();
        if (t == 0)
            atomicMax(d2max_p, (unsigned long long)__double_as_longlong(
                fmax(fmax(fmax(wred[0], wred[1]), fmax(wred[2], wred[3])), 0.0)));
        if (t < 128) {
            double m5[KNN];
            #pragma unroll
            for (int k = 0; k < KNN; k++) m5[k] = M[t * 21 + k];   // partial 0 (sorted)
            merge5s(m5, &M[t * 21 + 5]);
            merge5s(m5, &M[t * 21 + 10]);
            merge5s(m5, &M[t * 21 + 15]);
            double* outp = &rec_tr[(size_t)blockIdx.x * (TP * KNN) + t * KNN];
            #pragma unroll
            for (int k = 0; k < KNN; k++) outp[k] = m5[k];
        }
    } else {
        __syncthreads();
        if (t == 0)
            atomicMax(d2max_p, (unsigned long long)__double_as_longlong(
                fmax(fmax(fmax(wred[0], wred[1]), fmax(wred[2], wred[3])), 0.0)));
    }
}

// ---------------------------------------------------------------------------
// Merge symA records -> density.  Records are sorted ascending.
// ---------------------------------------------------------------------------
__global__ void density_merge_sym_kernel(const double* __restrict__ rec_dir,
                                         const double* __restrict__ rec_tr,
                                         const float* __restrict__ noise,
                                         double* __restrict__ density)
{
    int i = blockIdx.x * blockDim.x + threadIdx.x;
    if (i >= N) return;
    int T = i >> 7, r = i & 127;
    double t5[KNN];
    #pragma unroll
    for (int k = 0; k < KNN; k++) t5[k] = 1e300;

    for (int bj = T; bj < NTILE; bj++) {
        int p = bj * (bj + 1) / 2 + T;
        merge5s(t5, &rec_dir[(size_t)p * (TP * KNN) + r * KNN]);
    }
    int cumT = T * (T + 1) / 2;
    for (int b2 = 0; b2 < T; b2++) {
        merge5s(t5, &rec_tr[(size_t)(cumT + b2) * (TP * KNN) + r * KNN]);
    }
    // t5 sorted ascending; sum in ascending order (matches reference)
    double s2 = 0.0;
    #pragma unroll
    for (int k = 0; k < KNN; k++) {
        double z = t5[k] > 0.0 ? t5[k] : 0.0;
        double d = sqrt(z) / SQRT_C;
        s2 += d * d;
    }
    density[i] = exp(-s2 / 5.0) + (double)(noise[i] * 1e-6f);
}

// ---------------------------------------------------------------------------
// symB: tile-pair GEMM + masked row/col mins, shuffle-reduced, atomicMin.
// ---------------------------------------------------------------------------
__launch_bounds__(256, 2)
__global__ void symB_kernel(const float* __restrict__ X,
                            const double* __restrict__ sq,
                            const double* __restrict__ density,
                            unsigned long long* __restrict__ gmin)
{
    __shared__ __align__(16) double S[2 * CH * PJ];
    __shared__ double Drow[TP], Dcol[TP];
    double* As = S;
    double* Bs = S + CH * PJ;

    const int t  = threadIdx.x;
    const int tx = t & 15;
    const int ty = t >> 4;
    int bi, bj;
    pair_decode(blockIdx.x, bi, bj);
    const int i0 = bi * TP, j0 = bj * TP;
    const float4* X4 = (const float4*)X;

    if (t < 128) Drow[t] = density[i0 + t];
    else Dcol[t - 128] = density[j0 + t - 128];
    __syncthreads();

    double acc[8][8];
    #pragma unroll
    for (int r = 0; r < 8; r++)
        #pragma unroll
        for (int s = 0; s < 8; s++) acc[r][s] = 0.0;

    GEMM_BODY(acc, As, Bs, X4, i0, j0, t, tx, ty)

    double sqa[8], sqj[8], di[8], dj[8], dmr[8], dmc[8];
    #pragma unroll
    for (int r = 0; r < 8; r++) { sqa[r] = sq[i0 + 8 * ty + r]; di[r] = Drow[8 * ty + r]; dmr[r] = 1e300; }
    #pragma unroll
    for (int s = 0; s < 8; s++) {
        int col = 32 * (s >> 1) + 2 * tx + (s & 1);
        sqj[s] = sq[j0 + col];
        dj[s] = Dcol[col];
        dmc[s] = 1e300;
    }

    #pragma unroll
    for (int r = 0; r < 8; r++)
        #pragma unroll
        for (int s = 0; s < 8; s++) {
            double v = sqa[r] + sqj[s] - 2.0 * acc[r][s];
            if (dj[s] > di[r]) dmr[r] = fmin(dmr[r], v);
            if (di[r] > dj[s]) dmc[s] = fmin(dmc[s], v);
        }

    // rows: butterfly min over tx lanes; root atomicMin (scalar bfly is safe)
    #pragma unroll
    for (int r = 0; r < 8; r++) {
        #pragma unroll
        for (int m = 1; m <= 8; m <<= 1)
            dmr[r] = fmin(dmr[r], __shfl_xor(dmr[r], m, 64));
    }
    if (tx == 0) {
        #pragma unroll
        for (int r = 0; r < 8; r++)
            if (dmr[r] < 9.9e299) atomicMin(&gmin[i0 + 8 * ty + r], dmap(dmr[r]));
    }
    // cols: intra-wave ty butterfly; wave-root atomicMin (4 per col)
    if (bi != bj) {
        #pragma unroll
        for (int s = 0; s < 8; s++) {
            #pragma unroll
            for (int m = 16; m <= 32; m <<= 1)
                dmc[s] = fmin(dmc[s], __shfl_xor(dmc[s], m, 64));
        }
        if (((t >> 4) & 3) == 0) {
            #pragma unroll
            for (int s = 0; s < 8; s++) {
                if (dmc[s] < 9.9e299) {
                    int col = 32 * (s >> 1) + 2 * tx + (s & 1);
                    atomicMin(&gmin[j0 + col], dmap(dmc[s]));
                }
            }
        }
    }
}

// ---------------------------------------------------------------------------
__global__ void score_sym_kernel(const unsigned long long* __restrict__ gmin,
                                 const double* __restrict__ density,
                                 const unsigned long long* __restrict__ d2max_p,
                                 double* __restrict__ score)
{
    int i = blockIdx.x * blockDim.x + threadIdx.x;
    if (i >= N) return;
    unsigned long long u = gmin[i];
    double d2m = __longlong_as_double((long long)(*d2max_p));
    double distmax = sqrt(fmax(d2m, 0.0)) / SQRT_C;
    double dp;
    if (u == 0xFFFFFFFFFFFFFFFFull) {
        dp = distmax;
    } else {
        double dmin = dunmap(u);
        dp = sqrt(fmax(dmin, 0.0)) / SQRT_C;
    }
    score[i] = dp * density[i];
}

// ---------------------------------------------------------------------------
// Stable descending rank; 256 blocks, 8-way j-split per row, shuffle reduce.
// ---------------------------------------------------------------------------
__launch_bounds__(256)
__global__ void rank_kernel(const double* __restrict__ score, int* __restrict__ out)
{
    __shared__ double Ss[N];   // 64 KB
    for (int k = 0; k < N / 256; k++) {
        int idx = threadIdx.x + 256 * k;
        Ss[idx] = score[idx];
    }
    __syncthreads();
    int il = threadIdx.x >> 3;          // 0..31
    int ch = threadIdx.x & 7;           // 0..7
    int i = blockIdx.x * 32 + il;
    double si = Ss[i];
    int cnt = 0;
    for (int q = 0; q < N / 8; q++) {
        int j = ch + (q << 3);
        double sj = Ss[j];
        cnt += (sj > si) || (sj == si && j < i);
    }
    cnt += __shfl_down(cnt, 4, 8);
    cnt += __shfl_down(cnt, 2, 8);
    cnt += __shfl_down(cnt, 1, 8);
    if (ch == 0 && cnt < NC) out[cnt] = i;
}

// ---------------------------------------------------------------------------
extern "C" void kernel_launch(void* const* d_in, const int* in_sizes, int n_in,
                              void* d_out, int out_size, void* d_ws, size_t ws_size,
                              hipStream_t stream) {
    const float* X = (const float*)d_in[0];
    int* out = (int*)d_out;

    double* ws      = (double*)d_ws;
    double* sq      = ws;                      // 8192
    double* density = ws + 8192;               // 8192
    double* score   = ws + 16384;              // 8192
    unsigned long long* d2max = (unsigned long long*)(ws + 24576);
    unsigned long long* gmin  = (unsigned long long*)(ws + 24584);  // 8192
    float*  noise   = (float*)(ws + 32776);    // 8192 floats

    const size_t rec_bytes = (size_t)NPAIR * TP * KNN * sizeof(double);  // 10.65 MB
    const size_t base_need = 4ull * 1024 * 1024;
    double* rec_dir = (double*)((char*)d_ws + base_need);
    double* rec_tr  = (double*)((char*)d_ws + base_need + rec_bytes);

    init_kernel<<<N / 256, 256, 0, stream>>>(d2max, gmin);
    sq_kernel<<<N / 4, 256, 0, stream>>>(X, sq);
    noise_kernel<<<(N / 2) / 256, 256, 0, stream>>>(noise);

    symA_kernel<<<NPAIR, 256, 0, stream>>>(X, sq, rec_dir, rec_tr, d2max);
    density_merge_sym_kernel<<<N / 256, 256, 0, stream>>>(rec_dir, rec_tr, noise, density);
    symB_kernel<<<NPAIR, 256, 0, stream>>>(X, sq, density, gmin);
    score_sym_kernel<<<N / 256, 256, 0, stream>>>(gmin, density, d2max, score);
    rank_kernel<<<N / 32, 256, 0, stream>>>(score, out);
}

// Round 15
// 493.554 us; speedup vs baseline: 1.5035x; 1.0806x over previous
//
#include <hip/hip_runtime.h>
#include <math.h>

#define N 8192
#define C 128
#define NC 256
#define KNN 5

#define TP 128                        // tile size
#define NTILE (N / TP)                // 64
#define NPAIR (NTILE * (NTILE + 1) / 2)   // 2080
#define CH 16                         // channels per staging chunk
#define PJ 130                        // LDS pitch over row-dim (doubles)
#define SQRT_C 11.313708498984761     // sqrt(128)

typedef double d4 __attribute__((ext_vector_type(4)));

static __device__ __forceinline__ unsigned rotl32(unsigned x, unsigned r) {
    return (x << r) | (x >> (32u - r));
}

// order-preserving double -> uint64 map (ascending)
static __device__ __forceinline__ unsigned long long dmap(double x) {
    long long b = __double_as_longlong(x);
    unsigned long long u = (unsigned long long)b;
    return (b >= 0) ? (u | 0x8000000000000000ull) : ~u;
}
static __device__ __forceinline__ double dunmap(unsigned long long u) {
    if (u & 0x8000000000000000ull) return __longlong_as_double((long long)(u ^ 0x8000000000000000ull));
    return __longlong_as_double((long long)(~u));
}

// ---------------------------------------------------------------------------
// Branchless sorted top-5 (ascending).  (proven R13)
static __device__ __forceinline__ void ins5s(double (&m)[KNN], double v) {
    m[4] = fmin(m[4], fmax(m[3], v));
    m[3] = fmin(m[3], fmax(m[2], v));
    m[2] = fmin(m[2], fmax(m[1], v));
    m[1] = fmin(m[1], fmax(m[0], v));
    m[0] = fmin(m[0], v);
}
static __device__ __forceinline__ void sort5(double (&m)[KNN]) {
    double lo, hi;
#define CE(i, j) lo = fmin(m[i], m[j]); hi = fmax(m[i], m[j]); m[i] = lo; m[j] = hi;
    CE(0,1) CE(3,4) CE(2,4) CE(2,3) CE(0,3) CE(0,2) CE(1,4) CE(1,3) CE(1,2)
#undef CE
}
// bitonic top-5 butterfly merge (snapshot-before-mutate)  (proven R13)
static __device__ __forceinline__ void bfly5s(double (&m)[KNN], int mask) {
    double pv[KNN];
    #pragma unroll
    for (int k = 0; k < KNN; k++) pv[k] = __shfl_xor(m[4 - k], mask, 64);
    #pragma unroll
    for (int k = 0; k < KNN; k++) m[k] = fmin(m[k], pv[k]);
    sort5(m);
}
static __device__ __forceinline__ void merge5s(double (&m)[KNN], const double* l) {
    #pragma unroll
    for (int k = 0; k < KNN; k++) m[k] = fmin(m[k], l[4 - k]);
    sort5(m);
}

// ---------------------------------------------------------------------------
// f64 MFMA D-layout probe: A[m][k]=m, B[k][n]=[n==0] -> D[i][0]=4i (K=4).
// Lane (g, r==0) holds col 0 of its 4 rows; every lane fetches its group
// root's pd[j] and recovers its own row-in-tile for acc reg j.  No layout
// ordering assumption (R14 failed by assuming row=4g+reg).
static __device__ __forceinline__ void probe_rows(int t, int r, int (&irow)[4]) {
    d4 pd = (d4){0.0, 0.0, 0.0, 0.0};
    pd = __builtin_amdgcn_mfma_f64_16x16x4f64((double)r, (r == 0) ? 1.0 : 0.0,
                                              pd, 0, 0, 0);
    #pragma unroll
    for (int j = 0; j < 4; j++) {
        double rv = __shfl(pd[j], t & 48, 64);   // group root lane 16*g
        irow[j] = (int)(rv * 0.25);
    }
}

// ---------------------------------------------------------------------------
__global__ void init_kernel(unsigned long long* d2max, unsigned long long* gmin) {
    int i = blockIdx.x * blockDim.x + threadIdx.x;
    if (i < N) gmin[i] = 0xFFFFFFFFFFFFFFFFull;
    if (i == 0) *d2max = 0ull;
}

// ---------------------------------------------------------------------------
__global__ void sq_kernel(const float* __restrict__ X, double* __restrict__ sq) {
    int wave = (blockIdx.x * blockDim.x + threadIdx.x) >> 6;
    int lane = threadIdx.x & 63;
    if (wave >= N) return;
    double v0 = (double)X[wave * C + lane];
    double v1 = (double)X[wave * C + 64 + lane];
    double s = v0 * v0 + v1 * v1;
    #pragma unroll
    for (int off = 32; off > 0; off >>= 1) s += __shfl_down(s, off, 64);
    if (lane == 0) sq[wave] = s;
}

// ---------------------------------------------------------------------------
// JAX threefry2x32: uniform(key(1), (1,8192))
// ---------------------------------------------------------------------------
__global__ void noise_kernel(float* __restrict__ noise) {
    int j = blockIdx.x * blockDim.x + threadIdx.x;
    if (j >= N / 2) return;
    const unsigned ks0 = 0u, ks1 = 1u;
    const unsigned ks2 = 0x1BD11BDAu ^ ks0 ^ ks1;
    unsigned x0 = (unsigned)j + ks0;
    unsigned x1 = (unsigned)(j + N / 2) + ks1;
    const unsigned rotA[4] = {13u, 15u, 26u, 6u};
    const unsigned rotB[4] = {17u, 29u, 16u, 24u};
    #pragma unroll
    for (int r = 0; r < 4; r++) { x0 += x1; x1 = rotl32(x1, rotA[r]); x1 ^= x0; }
    x0 += ks1; x1 += ks2 + 1u;
    #pragma unroll
    for (int r = 0; r < 4; r++) { x0 += x1; x1 = rotl32(x1, rotB[r]); x1 ^= x0; }
    x0 += ks2; x1 += ks0 + 2u;
    #pragma unroll
    for (int r = 0; r < 4; r++) { x0 += x1; x1 = rotl32(x1, rotA[r]); x1 ^= x0; }
    x0 += ks0; x1 += ks1 + 3u;
    #pragma unroll
    for (int r = 0; r < 4; r++) { x0 += x1; x1 = rotl32(x1, rotB[r]); x1 ^= x0; }
    x0 += ks1; x1 += ks2 + 4u;
    #pragma unroll
    for (int r = 0; r < 4; r++) { x0 += x1; x1 = rotl32(x1, rotA[r]); x1 ^= x0; }
    x0 += ks2; x1 += ks0 + 5u;
    unsigned b0 = (x0 >> 9) | 0x3f800000u;
    unsigned b1 = (x1 >> 9) | 0x3f800000u;
    noise[j]         = __uint_as_float(b0) - 1.0f;
    noise[j + N / 2] = __uint_as_float(b1) - 1.0f;
}

// p = bj*(bj+1)/2 + bi, bi <= bj
static __device__ __forceinline__ void pair_decode(int p, int& bi, int& bj) {
    int b = (int)((sqrt(8.0 * (double)p + 1.0) - 1.0) * 0.5);
    while ((b + 1) * (b + 2) / 2 <= p) b++;
    while (b * (b + 1) / 2 > p) b--;
    bj = b;
    bi = p - b * (b + 1) / 2;
}

// ---------------------------------------------------------------------------
// MFMA f64 GEMM body: 128x128 tile-pair.  Wave w owns rows w*32..w*32+31
// (2 row-tiles of 16) x all 128 cols (8 col-tiles).  acc[2][8] d4/lane.
// f64 [c][row] staging (pitch PJ), 8 chunks of 16 channels, reg prefetch.
// A: m=l&15, k=l>>4 ; B: k=l>>4, n=l&15 ; D: col=l&15, row via probe_rows.
// ---------------------------------------------------------------------------
#define MFMA_GEMM_BODY(acc, As, Bs, X4, i0, j0, t, r, g, w32)                  \
    {                                                                          \
        float4 pa[2], pb[2];                                                   \
        _Pragma("unroll")                                                      \
        for (int q = 0; q < 2; q++) {                                          \
            int flat = t + 256 * q;                                            \
            int row = flat >> 2, c4 = flat & 3;                                \
            pa[q] = X4[(size_t)(i0 + row) * 32 + c4];                          \
            pb[q] = X4[(size_t)(j0 + row) * 32 + c4];                          \
        }                                                                      \
        for (int ck = 0; ck < 8; ck++) {                                       \
            _Pragma("unroll")                                                  \
            for (int q = 0; q < 2; q++) {                                      \
                int flat = t + 256 * q;                                        \
                int row = flat >> 2, c4 = flat & 3;                            \
                As[(4 * c4 + 0) * PJ + row] = (double)pa[q].x;                 \
                As[(4 * c4 + 1) * PJ + row] = (double)pa[q].y;                 \
                As[(4 * c4 + 2) * PJ + row] = (double)pa[q].z;                 \
                As[(4 * c4 + 3) * PJ + row] = (double)pa[q].w;                 \
                Bs[(4 * c4 + 0) * PJ + row] = (double)pb[q].x;                 \
                Bs[(4 * c4 + 1) * PJ + row] = (double)pb[q].y;                 \
                Bs[(4 * c4 + 2) * PJ + row] = (double)pb[q].z;                 \
                Bs[(4 * c4 + 3) * PJ + row] = (double)pb[q].w;                 \
            }                                                                  \
            __syncthreads();                                                   \
            if (ck < 7) {                                                      \
                _Pragma("unroll")                                              \
                for (int q = 0; q < 2; q++) {                                  \
                    int flat = t + 256 * q;                                    \
                    int row = flat >> 2, c4 = flat & 3;                        \
                    pa[q] = X4[(size_t)(i0 + row) * 32 + (ck + 1) * 4 + c4];   \
                    pb[q] = X4[(size_t)(j0 + row) * 32 + (ck + 1) * 4 + c4];   \
                }                                                              \
            }                                                                  \
            _Pragma("unroll")                                                  \
            for (int ks = 0; ks < 4; ks++) {                                   \
                int cc = 4 * ks + g;                                           \
                double a0 = As[cc * PJ + w32 + r];                             \
                double a1 = As[cc * PJ + w32 + 16 + r];                        \
                double bv[8];                                                  \
                _Pragma("unroll")                                              \
                for (int nt = 0; nt < 8; nt++) bv[nt] = Bs[cc * PJ + nt * 16 + r]; \
                _Pragma("unroll")                                              \
                for (int nt = 0; nt < 8; nt++)                                 \
                    acc[0][nt] = __builtin_amdgcn_mfma_f64_16x16x4f64(a0, bv[nt], acc[0][nt], 0, 0, 0); \
                _Pragma("unroll")                                              \
                for (int nt = 0; nt < 8; nt++)                                 \
                    acc[1][nt] = __builtin_amdgcn_mfma_f64_16x16x4f64(a1, bv[nt], acc[1][nt], 0, 0, 0); \
            }                                                                  \
            __syncthreads();                                                   \
        }                                                                      \
    }

// lane-owned outputs: rows w32 + mt*16 + irow[j], cols nt*16 + r

// ---------------------------------------------------------------------------
// symA: MFMA d2 GEMM + sorted top-5 epilogue (rows bfly 1-8, cols 16/32+LDS).
// ---------------------------------------------------------------------------
__launch_bounds__(256, 2)
__global__ void symA_kernel(const float* __restrict__ X,
                            const double* __restrict__ sq,
                            double* __restrict__ rec_dir,
                            double* __restrict__ rec_tr,
                            unsigned long long* __restrict__ d2max_p)
{
    __shared__ __align__(16) double S[2 * CH * PJ];   // 33,280 B; reused as M
    __shared__ double wred[4];
    double* As = S;
    double* Bs = S + CH * PJ;

    const int t = threadIdx.x;
    const int r = t & 15;
    const int g = (t >> 4) & 3;
    const int w = t >> 6;
    const int w32 = w * 32;
    int bi, bj;
    pair_decode(blockIdx.x, bi, bj);
    const int i0 = bi * TP, j0 = bj * TP;
    const float4* X4 = (const float4*)X;

    int irow[4];
    probe_rows(t, r, irow);

    d4 acc[2][8];
    #pragma unroll
    for (int mt = 0; mt < 2; mt++)
        #pragma unroll
        for (int nt = 0; nt < 8; nt++) acc[mt][nt] = (d4){0.0, 0.0, 0.0, 0.0};

    MFMA_GEMM_BODY(acc, As, Bs, X4, i0, j0, t, r, g, w32)

    // d2 in place + block max
    double sqa[2][4], sqj[8];
    #pragma unroll
    for (int mt = 0; mt < 2; mt++)
        #pragma unroll
        for (int j = 0; j < 4; j++) sqa[mt][j] = sq[i0 + w32 + mt * 16 + irow[j]];
    #pragma unroll
    for (int nt = 0; nt < 8; nt++) sqj[nt] = sq[j0 + nt * 16 + r];
    double rmax = 0.0;
    #pragma unroll
    for (int mt = 0; mt < 2; mt++)
        #pragma unroll
        for (int nt = 0; nt < 8; nt++)
            #pragma unroll
            for (int j = 0; j < 4; j++) {
                double v = sqa[mt][j] + sqj[nt] - 2.0 * acc[mt][nt][j];
                acc[mt][nt][j] = v;
                rmax = fmax(rmax, v);
            }
    #pragma unroll
    for (int off = 32; off > 0; off >>= 1) rmax = fmax(rmax, __shfl_down(rmax, off, 64));
    if ((t & 63) == 0) wred[w] = rmax;

    // ---- rows: lane scans 8 nt values; bfly over r lanes; r==0 writes.
    // For fixed (mt,j) all 16 lanes of a g-group hold the same row.
    #pragma unroll
    for (int mt = 0; mt < 2; mt++)
        #pragma unroll
        for (int j = 0; j < 4; j++) {
            double m5[KNN];
            #pragma unroll
            for (int k = 0; k < KNN; k++) m5[k] = 1e300;
            #pragma unroll
            for (int nt = 0; nt < 8; nt++) ins5s(m5, acc[mt][nt][j]);
            bfly5s(m5, 1); bfly5s(m5, 2); bfly5s(m5, 4); bfly5s(m5, 8);
            if (r == 0) {
                int row = w32 + mt * 16 + irow[j];
                double* outp = &rec_dir[(size_t)blockIdx.x * (TP * KNN) + row * KNN];
                #pragma unroll
                for (int k = 0; k < KNN; k++) outp[k] = m5[k];
            }
        }

    // ---- cols (off-diagonal): scan 8 (mt,j); bfly over g (16,32); LDS merge
    if (bi != bj) {
        double* M = S;   // [col][21] : 4 wave-partials x 5
        #pragma unroll
        for (int nt = 0; nt < 8; nt++) {
            double m5[KNN];
            #pragma unroll
            for (int k = 0; k < KNN; k++) m5[k] = 1e300;
            #pragma unroll
            for (int mt = 0; mt < 2; mt++)
                #pragma unroll
                for (int j = 0; j < 4; j++) ins5s(m5, acc[mt][nt][j]);
            bfly5s(m5, 16); bfly5s(m5, 32);
            if (g == 0) {
                int col = nt * 16 + r;
                #pragma unroll
                for (int k = 0; k < KNN; k++) M[col * 21 + w * 5 + k] = m5[k];
            }
        }
        __syncthreads();
        if (t == 0)
            atomicMax(d2max_p, (unsigned long long)__double_as_longlong(
                fmax(fmax(fmax(wred[0], wred[1]), fmax(wred[2], wred[3])), 0.0)));
        if (t < 128) {
            double m5[KNN];
            #pragma unroll
            for (int k = 0; k < KNN; k++) m5[k] = M[t * 21 + k];
            merge5s(m5, &M[t * 21 + 5]);
            merge5s(m5, &M[t * 21 + 10]);
            merge5s(m5, &M[t * 21 + 15]);
            double* outp = &rec_tr[(size_t)blockIdx.x * (TP * KNN) + t * KNN];
            #pragma unroll
            for (int k = 0; k < KNN; k++) outp[k] = m5[k];
        }
    } else {
        __syncthreads();
        if (t == 0)
            atomicMax(d2max_p, (unsigned long long)__double_as_longlong(
                fmax(fmax(fmax(wred[0], wred[1]), fmax(wred[2], wred[3])), 0.0)));
    }
}

// ---------------------------------------------------------------------------
// Merge symA records -> density.  Records sorted ascending.
// ---------------------------------------------------------------------------
__global__ void density_merge_sym_kernel(const double* __restrict__ rec_dir,
                                         const double* __restrict__ rec_tr,
                                         const float* __restrict__ noise,
                                         double* __restrict__ density)
{
    int i = blockIdx.x * blockDim.x + threadIdx.x;
    if (i >= N) return;
    int T = i >> 7, r = i & 127;
    double t5[KNN];
    #pragma unroll
    for (int k = 0; k < KNN; k++) t5[k] = 1e300;

    for (int bj = T; bj < NTILE; bj++) {
        int p = bj * (bj + 1) / 2 + T;
        merge5s(t5, &rec_dir[(size_t)p * (TP * KNN) + r * KNN]);
    }
    int cumT = T * (T + 1) / 2;
    for (int b2 = 0; b2 < T; b2++) {
        merge5s(t5, &rec_tr[(size_t)(cumT + b2) * (TP * KNN) + r * KNN]);
    }
    double s2 = 0.0;
    #pragma unroll
    for (int k = 0; k < KNN; k++) {
        double z = t5[k] > 0.0 ? t5[k] : 0.0;
        double d = sqrt(z) / SQRT_C;
        s2 += d * d;
    }
    density[i] = exp(-s2 / 5.0) + (double)(noise[i] * 1e-6f);
}

// ---------------------------------------------------------------------------
// symB: MFMA GEMM + masked row/col mins, shuffle-reduced, atomicMin.
// ---------------------------------------------------------------------------
__launch_bounds__(256, 2)
__global__ void symB_kernel(const float* __restrict__ X,
                            const double* __restrict__ sq,
                            const double* __restrict__ density,
                            unsigned long long* __restrict__ gmin)
{
    __shared__ __align__(16) double S[2 * CH * PJ];
    __shared__ double Drow[TP], Dcol[TP];
    double* As = S;
    double* Bs = S + CH * PJ;

    const int t = threadIdx.x;
    const int r = t & 15;
    const int g = (t >> 4) & 3;
    const int w = t >> 6;
    const int w32 = w * 32;
    int bi, bj;
    pair_decode(blockIdx.x, bi, bj);
    const int i0 = bi * TP, j0 = bj * TP;
    const float4* X4 = (const float4*)X;

    int irow[4];
    probe_rows(t, r, irow);

    if (t < 128) Drow[t] = density[i0 + t];
    else Dcol[t - 128] = density[j0 + t - 128];
    __syncthreads();

    d4 acc[2][8];
    #pragma unroll
    for (int mt = 0; mt < 2; mt++)
        #pragma unroll
        for (int nt = 0; nt < 8; nt++) acc[mt][nt] = (d4){0.0, 0.0, 0.0, 0.0};

    MFMA_GEMM_BODY(acc, As, Bs, X4, i0, j0, t, r, g, w32)

    double sqa[2][4], di[2][4], sqj[8], dj[8], dmr[2][4], dmc[8];
    #pragma unroll
    for (int mt = 0; mt < 2; mt++)
        #pragma unroll
        for (int j = 0; j < 4; j++) {
            int row = w32 + mt * 16 + irow[j];
            sqa[mt][j] = sq[i0 + row];
            di[mt][j] = Drow[row];
            dmr[mt][j] = 1e300;
        }
    #pragma unroll
    for (int nt = 0; nt < 8; nt++) {
        int col = nt * 16 + r;
        sqj[nt] = sq[j0 + col];
        dj[nt] = Dcol[col];
        dmc[nt] = 1e300;
    }

    #pragma unroll
    for (int mt = 0; mt < 2; mt++)
        #pragma unroll
        for (int nt = 0; nt < 8; nt++)
            #pragma unroll
            for (int j = 0; j < 4; j++) {
                double v = sqa[mt][j] + sqj[nt] - 2.0 * acc[mt][nt][j];
                if (dj[nt] > di[mt][j]) dmr[mt][j] = fmin(dmr[mt][j], v);
                if (di[mt][j] > dj[nt]) dmc[nt] = fmin(dmc[nt], v);
            }

    // rows: scalar min butterfly over r lanes; r==0 atomicMin
    #pragma unroll
    for (int mt = 0; mt < 2; mt++)
        #pragma unroll
        for (int j = 0; j < 4; j++) {
            #pragma unroll
            for (int m = 1; m <= 8; m <<= 1)
                dmr[mt][j] = fmin(dmr[mt][j], __shfl_xor(dmr[mt][j], m, 64));
        }
    if (r == 0) {
        #pragma unroll
        for (int mt = 0; mt < 2; mt++)
            #pragma unroll
            for (int j = 0; j < 4; j++)
                if (dmr[mt][j] < 9.9e299) {
                    int row = w32 + mt * 16 + irow[j];
                    atomicMin(&gmin[i0 + row], dmap(dmr[mt][j]));
                }
    }
    // cols: butterfly over g (16,32); g==0 atomicMin (4 wave-partials/col)
    if (bi != bj) {
        #pragma unroll
        for (int nt = 0; nt < 8; nt++) {
            #pragma unroll
            for (int m = 16; m <= 32; m <<= 1)
                dmc[nt] = fmin(dmc[nt], __shfl_xor(dmc[nt], m, 64));
        }
        if (g == 0) {
            #pragma unroll
            for (int nt = 0; nt < 8; nt++)
                if (dmc[nt] < 9.9e299) {
                    int col = nt * 16 + r;
                    atomicMin(&gmin[j0 + col], dmap(dmc[nt]));
                }
        }
    }
}

// ---------------------------------------------------------------------------
__global__ void score_sym_kernel(const unsigned long long* __restrict__ gmin,
                                 const double* __restrict__ density,
                                 const unsigned long long* __restrict__ d2max_p,
                                 double* __restrict__ score)
{
    int i = blockIdx.x * blockDim.x + threadIdx.x;
    if (i >= N) return;
    unsigned long long u = gmin[i];
    double d2m = __longlong_as_double((long long)(*d2max_p));
    double distmax = sqrt(fmax(d2m, 0.0)) / SQRT_C;
    double dp;
    if (u == 0xFFFFFFFFFFFFFFFFull) {
        dp = distmax;
    } else {
        double dmin = dunmap(u);
        dp = sqrt(fmax(dmin, 0.0)) / SQRT_C;
    }
    score[i] = dp * density[i];
}

// ---------------------------------------------------------------------------
// Stable descending rank; 256 blocks, 8-way j-split per row, shuffle reduce.
// ---------------------------------------------------------------------------
__launch_bounds__(256)
__global__ void rank_kernel(const double* __restrict__ score, int* __restrict__ out)
{
    __shared__ double Ss[N];   // 64 KB
    for (int k = 0; k < N / 256; k++) {
        int idx = threadIdx.x + 256 * k;
        Ss[idx] = score[idx];
    }
    __syncthreads();
    int il = threadIdx.x >> 3;          // 0..31
    int ch = threadIdx.x & 7;           // 0..7
    int i = blockIdx.x * 32 + il;
    double si = Ss[i];
    int cnt = 0;
    for (int q = 0; q < N / 8; q++) {
        int j = ch + (q << 3);
        double sj = Ss[j];
        cnt += (sj > si) || (sj == si && j < i);
    }
    cnt += __shfl_down(cnt, 4, 8);
    cnt += __shfl_down(cnt, 2, 8);
    cnt += __shfl_down(cnt, 1, 8);
    if (ch == 0 && cnt < NC) out[cnt] = i;
}

// ---------------------------------------------------------------------------
extern "C" void kernel_launch(void* const* d_in, const int* in_sizes, int n_in,
                              void* d_out, int out_size, void* d_ws, size_t ws_size,
                              hipStream_t stream) {
    const float* X = (const float*)d_in[0];
    int* out = (int*)d_out;

    double* ws      = (double*)d_ws;
    double* sq      = ws;                      // 8192
    double* density = ws + 8192;               // 8192
    double* score   = ws + 16384;              // 8192
    unsigned long long* d2max = (unsigned long long*)(ws + 24576);
    unsigned long long* gmin  = (unsigned long long*)(ws + 24584);  // 8192
    float*  noise   = (float*)(ws + 32776);    // 8192 floats

    const size_t rec_bytes = (size_t)NPAIR * TP * KNN * sizeof(double);  // 10.65 MB
    const size_t base_need = 4ull * 1024 * 1024;
    double* rec_dir = (double*)((char*)d_ws + base_need);
    double* rec_tr  = (double*)((char*)d_ws + base_need + rec_bytes);

    init_kernel<<<N / 256, 256, 0, stream>>>(d2max, gmin);
    sq_kernel<<<N / 4, 256, 0, stream>>>(X, sq);
    noise_kernel<<<(N / 2) / 256, 256, 0, stream>>>(noise);

    symA_kernel<<<NPAIR, 256, 0, stream>>>(X, sq, rec_dir, rec_tr, d2max);
    density_merge_sym_kernel<<<N / 256, 256, 0, stream>>>(rec_dir, rec_tr, noise, density);
    symB_kernel<<<NPAIR, 256, 0, stream>>>(X, sq, density, gmin);
    score_sym_kernel<<<N / 256, 256, 0, stream>>>(gmin, density, d2max, score);
    rank_kernel<<<N / 32, 256, 0, stream>>>(score, out);
}